// Round 7
// baseline (167.761 us; speedup 1.0000x reference)
//
#include <hip/hip_runtime.h>

#define IN_F 4096
#define OUT_F 16384
#define M_ROWS 512

#define BM 512
#define BN 128
#define BK 32
#define KSPAN 2048
#define NKT (KSPAN / BK)   // 64
#define THREADS 512

typedef __bf16 bf16x8_t __attribute__((ext_vector_type(8)));
typedef float f32x4_t __attribute__((ext_vector_type(4)));
typedef int i32x4_t __attribute__((ext_vector_type(4)));

__device__ __forceinline__ void gld16(const void* g, void* l) {
    __builtin_amdgcn_global_load_lds(
        (const __attribute__((address_space(1))) void*)g,
        (__attribute__((address_space(3))) void*)l,
        16 /*bytes, literal*/, 0, 0);
}

// ---------------- pre-pass 1: x fp32 -> bf16 tiles, swizzled LDS image ----------------
// Tile t (128 tiles of 512x32) is the exact byte image gld_lds drops into LDS.
// LDS byte (r*64 + c'*16) must hold x[r][t*32 + (c' ^ s(r))*8 ..+8), s(r)=(r>>1)&3.
// This makes frag reads at slot g^s(r) conflict-free (8 distinct 16B groups / 16 lanes).
__global__ __launch_bounds__(256)
void xpack_kernel(const float* __restrict__ x, __bf16* __restrict__ xp) {
    const int tid = blockIdx.x * 256 + (int)threadIdx.x;  // 262144 threads
    const int e0 = tid * 8;
    const int tile = e0 >> 14;            // 16384 elems (32 KB) per tile
    const int rem = e0 & 16383;
    const int r = rem >> 5;               // 0..511
    const int cs = (rem >> 3) & 3;        // slot index
    const int c = cs ^ ((r >> 1) & 3);    // source k-chunk
    const float* src = x + (size_t)r * IN_F + tile * 32 + c * 8;
    f32x4_t a = *(const f32x4_t*)(src);
    f32x4_t b = *(const f32x4_t*)(src + 4);
    bf16x8_t o;
    o[0] = (__bf16)a[0]; o[1] = (__bf16)a[1]; o[2] = (__bf16)a[2]; o[3] = (__bf16)a[3];
    o[4] = (__bf16)b[0]; o[5] = (__bf16)b[1]; o[6] = (__bf16)b[2]; o[7] = (__bf16)b[3];
    *(bf16x8_t*)(xp + e0) = o;
}

// ---------------- pre-pass 2: out[r][c] = bias[c] (atomic accumulation target) ----------------
__global__ __launch_bounds__(256)
void bias_init_kernel(const float* __restrict__ bias, float* __restrict__ out) {
    const int idx = blockIdx.x * 256 + (int)threadIdx.x;   // 2M f32x4 stores
    const int c4 = idx & 4095;                             // 4096 f32x4 per row
    f32x4_t b = *(const f32x4_t*)(bias + c4 * 4);
    *(f32x4_t*)(out + (size_t)idx * 4) = b;
}

// ---------------- main GEMM: split-K, wave-tile 128x64, bf16 B, counted vmcnt ----------------
// grid 256 = 2 kh x 128 nt (kh per XCD-half: 2MB xp slice L2-resident; Wq read once).
// 8 waves (4m x 2n), 1 blk/CU. LDS 80 KB. Per CU/kt: 96 ds_read_b128 (conflict-free),
// 256 MFMA, 48 KB VMEM -> ~1500 cyc/kt floor.
__global__ __launch_bounds__(THREADS, 2)
void qgemm7_kernel(const __bf16* __restrict__ xp, const int* __restrict__ Wq,
                   const float* __restrict__ scales, float* __restrict__ out) {
    __shared__ __align__(16) unsigned char sA[2][BM * BK * 2];   // 2 x 32 KB bf16
    __shared__ __align__(16) unsigned char sB[2][BN * BK * 2];   // 2 x 8 KB bf16

    const int bid = (int)blockIdx.x;
    const int xcd = bid & 7;
    const int slot = bid >> 3;                 // 0..31
    const int kh = xcd >> 2;                   // XCDs 0-3 -> kh0, 4-7 -> kh1
    const int nt = (xcd & 3) * 32 + slot;      // 0..127
    const int bcol = nt * BN;
    const int kbase = kh * KSPAN;              // int32-elem offset into Wq rows
    const __bf16* xt = xp + (size_t)(kh * NKT) * (BM * BK);  // + kt*16384 elems

    const int t = (int)threadIdx.x;
    const int lane = t & 63;
    const int wid = t >> 6;                    // 8 waves
    const int wm = wid >> 1;                   // 0..3  (128-row stripe)
    const int wn = wid & 1;                    // 0..1  (64-col stripe)

    // ---- B staging: thread -> row rb (0..127), k-chunk cW (0..3), 8 int32 ----
    const int rb = t >> 2;
    const int cW = t & 3;
    const int* wg = Wq + (size_t)(bcol + rb) * IN_F + kbase + cW * 8;
    const int woffB = rb * 64 + ((cW ^ ((rb >> 1) & 3)) << 4);

    // ---- A DMA: 32 KB/kt = 4 gld16/thread; xp already the LDS byte image ----
    const int ldsA0 = wid * 1024;              // wave-uniform; HW adds lane*16

    // ---- fragment addresses (swizzle slot invariant under row+16: one base + imm offs) ----
    const int arow0 = wm * 128 + (lane & 15);
    const int g = lane >> 4;
    const int aoff = arow0 * 64 + ((g ^ ((arow0 >> 1) & 3)) << 4);   // + m*1024
    const int brow0 = wn * 64 + (lane & 15);
    const int boff = brow0 * 64 + ((g ^ ((brow0 >> 1) & 3)) << 4);   // + n*1024

    f32x4_t acc[8][4];
#pragma unroll
    for (int m = 0; m < 8; ++m)
#pragma unroll
        for (int n = 0; n < 4; ++n) {
            f32x4_t z = {0.f, 0.f, 0.f, 0.f};
            acc[m][n] = z;
        }

    i32x4_t bv[2];

#define ISSUE_A(KT_, PB_)                                               \
    do {                                                                \
        const __bf16* sa_ = xt + (size_t)(KT_) * (BM * BK) + t * 8;     \
        unsigned char* da_ = &sA[PB_][0] + ldsA0;                       \
        gld16(sa_, da_);                                                \
        gld16(sa_ + 4096, da_ + 8192);                                  \
        gld16(sa_ + 8192, da_ + 16384);                                 \
        gld16(sa_ + 12288, da_ + 24576);                                \
    } while (0)

#define ISSUE_B(KT_)                                                    \
    do {                                                                \
        const int* p_ = wg + (size_t)(KT_) * BK;                        \
        bv[0] = *(const i32x4_t*)(p_);                                  \
        bv[1] = *(const i32x4_t*)(p_ + 4);                              \
    } while (0)

#define WRITE_B(PB_)                                                    \
    do {                                                                \
        bf16x8_t w_;                                                    \
        _Pragma("unroll") for (int j_ = 0; j_ < 4; ++j_) {              \
            w_[j_] = (__bf16)(float)bv[0][j_];                          \
            w_[4 + j_] = (__bf16)(float)bv[1][j_];                      \
        }                                                               \
        *(bf16x8_t*)(&sB[PB_][0] + woffB) = w_;                         \
    } while (0)

    // -------- prologue: tile 0 staged, B(1) in regs --------
    ISSUE_A(0, 0);
    ISSUE_B(0);
    asm volatile("s_waitcnt vmcnt(0)" ::: "memory");
    WRITE_B(0);
    ISSUE_B(1);

#pragma unroll 1
    for (int kt = 0; kt < NKT; ++kt) {
        const int cur = kt & 1;
        // entry: outstanding = A(kt)[4 oldest] + B(kt+1)[2]; retire A(kt), keep B in flight.
        asm volatile("s_waitcnt vmcnt(2) lgkmcnt(0)" ::: "memory");
        __builtin_amdgcn_sched_barrier(0);
        __builtin_amdgcn_s_barrier();
        __builtin_amdgcn_sched_barrier(0);

        // prefetch A(kt+1) into the buffer whose readers finished last kt
        {
            const int kn = (kt + 1 < NKT) ? kt + 1 : NKT - 1;
            ISSUE_A(kn, cur ^ 1);
        }

        // B fragments (4 ds_read_b128, conflict-free)
        bf16x8_t bf[4];
#pragma unroll
        for (int n = 0; n < 4; ++n)
            bf[n] = *(const bf16x8_t*)(&sB[cur][0] + boff + n * 1024);

        __builtin_amdgcn_sched_barrier(0);
        // B(kt+1) regs ready (outstanding after: A(kt+1)[4]); write + refill
        asm volatile("s_waitcnt vmcnt(4)" ::: "memory");
        WRITE_B(cur ^ 1);
        {
            const int kn2 = (kt + 2 < NKT) ? kt + 2 : NKT - 1;
            ISSUE_B(kn2);
        }
        __builtin_amdgcn_sched_barrier(0);

        // A fragments + MFMA in two m-halves (VGPR control)
#pragma unroll
        for (int mh = 0; mh < 2; ++mh) {
            bf16x8_t af[4];
#pragma unroll
            for (int m = 0; m < 4; ++m)
                af[m] = *(const bf16x8_t*)(&sA[cur][0] + aoff + (mh * 4 + m) * 1024);
            __builtin_amdgcn_s_setprio(1);
#pragma unroll
            for (int m = 0; m < 4; ++m)
#pragma unroll
                for (int n = 0; n < 4; ++n)
                    acc[mh * 4 + m][n] = __builtin_amdgcn_mfma_f32_16x16x32_bf16(
                        af[m], bf[n], acc[mh * 4 + m][n], 0, 0, 0);
            __builtin_amdgcn_s_setprio(0);
        }
    }
#undef ISSUE_A
#undef ISSUE_B
#undef WRITE_B

    // ---- epilogue: scale + atomic accumulate into bias-initialized out ----
    // C/D layout: col = lane&15, row = (lane>>4)*4 + reg (m89-verified, r1-r6-validated)
    const int orow0 = wm * 128 + ((lane >> 4) << 2);
    const int ocol0 = bcol + wn * 64 + (lane & 15);
#pragma unroll
    for (int n = 0; n < 4; ++n) {
        const int c = ocol0 + n * 16;
        const float sc = scales[c];
#pragma unroll
        for (int m = 0; m < 8; ++m) {
            const int r = orow0 + m * 16;
            float* po = out + (size_t)r * OUT_F + c;
#pragma unroll
            for (int j = 0; j < 4; ++j) {
                __hip_atomic_fetch_add(po + (size_t)j * OUT_F, acc[m][n][j] * sc,
                                       __ATOMIC_RELAXED, __HIP_MEMORY_SCOPE_AGENT);
            }
        }
    }
}

// ---------------- fallback (no workspace): round-1 kernel, known-correct ----------------
__global__ __launch_bounds__(256, 2)
void qgemm_fallback(const float* __restrict__ x, const int* __restrict__ Wq,
                    const float* __restrict__ scales, const float* __restrict__ bias,
                    float* __restrict__ out) {
    __shared__ __align__(16) unsigned char fA[128 * 64 * 2];
    __shared__ __align__(16) unsigned char fB[128 * 64 * 2];

    const int bid = (int)blockIdx.x;
    const int gsw = (bid & 7) * 64 + (bid >> 3);
    const int mt = gsw & 3;
    const int ntf = gsw >> 2;
    const int brow = mt * 128;
    const int bcolf = ntf * 128;

    const int t = (int)threadIdx.x;
    const int lane = t & 63;
    const int wid = t >> 6;
    const int wr = wid >> 1;
    const int wc = wid & 1;

    const int srow = t >> 4;
    const int sc4 = t & 15;

    const float* xg = x + (size_t)(brow + srow) * IN_F + sc4 * 4;
    const int* wgf = Wq + (size_t)(bcolf + srow) * IN_F + sc4 * 4;

    f32x4_t acc[4][4];
#pragma unroll
    for (int i = 0; i < 4; ++i)
#pragma unroll
        for (int j = 0; j < 4; ++j) {
            f32x4_t z = {0.f, 0.f, 0.f, 0.f};
            acc[i][j] = z;
        }

    const int frow_a = wr * 64 + (lane & 15);
    const int frow_b = wc * 64 + (lane & 15);
    const int fk = (lane >> 4) * 16;

#pragma unroll 1
    for (int kt = 0; kt < IN_F / 64; ++kt) {
        const int k0 = kt * 64;
        f32x4_t av[8];
        i32x4_t bvf[8];
#pragma unroll
        for (int i = 0; i < 8; ++i) {
            av[i] = *(const f32x4_t*)(xg + k0 + (size_t)i * 16 * IN_F);
            bvf[i] = *(const i32x4_t*)(wgf + k0 + (size_t)i * 16 * IN_F);
        }
        __syncthreads();
#pragma unroll
        for (int i = 0; i < 8; ++i) {
            const int row = srow + i * 16;
            unsigned off = (unsigned)(row * 128 + sc4 * 8);
            off ^= (unsigned)(row & 7) << 4;
            __bf16 pa[4], pb[4];
#pragma unroll
            for (int j = 0; j < 4; ++j) {
                pa[j] = (__bf16)av[i][j];
                pb[j] = (__bf16)(float)bvf[i][j];
            }
            *(unsigned long long*)(fA + off) = *(unsigned long long*)pa;
            *(unsigned long long*)(fB + off) = *(unsigned long long*)pb;
        }
        __syncthreads();
#pragma unroll
        for (int ks = 0; ks < 2; ++ks) {
            bf16x8_t afv[4], bfv[4];
#pragma unroll
            for (int m = 0; m < 4; ++m) {
                const int row = frow_a + m * 16;
                afv[m] = *(const bf16x8_t*)(fA + (row * 128 + ((ks * 64 + fk) ^ ((row & 7) << 4))));
            }
#pragma unroll
            for (int n = 0; n < 4; ++n) {
                const int row = frow_b + n * 16;
                bfv[n] = *(const bf16x8_t*)(fB + (row * 128 + ((ks * 64 + fk) ^ ((row & 7) << 4))));
            }
#pragma unroll
            for (int m = 0; m < 4; ++m)
#pragma unroll
                for (int n = 0; n < 4; ++n)
                    acc[m][n] = __builtin_amdgcn_mfma_f32_16x16x32_bf16(
                        afv[m], bfv[n], acc[m][n], 0, 0, 0);
        }
    }

    const int orow = brow + wr * 64 + ((lane >> 4) << 2);
    const int ocol = bcolf + wc * 64 + (lane & 15);
#pragma unroll
    for (int n = 0; n < 4; ++n) {
        const int c = ocol + n * 16;
        const float sc = scales[c];
        const float bs = bias[c];
#pragma unroll
        for (int m = 0; m < 4; ++m) {
            const int r = orow + m * 16;
            float* po = out + (size_t)r * OUT_F + c;
#pragma unroll
            for (int j = 0; j < 4; ++j) {
                po[(size_t)j * OUT_F] = acc[m][n][j] * sc + bs;
            }
        }
    }
}

extern "C" void kernel_launch(void* const* d_in, const int* in_sizes, int n_in,
                              void* d_out, int out_size, void* d_ws, size_t ws_size,
                              hipStream_t stream) {
    const float* x = (const float*)d_in[0];
    const int* Wq = (const int*)d_in[1];
    const float* scales = (const float*)d_in[2];
    const float* bias = (const float*)d_in[3];
    float* out = (float*)d_out;

    const size_t xp_bytes = (size_t)M_ROWS * IN_F * 2;  // 4 MB
    const bool pre = (ws_size >= xp_bytes) && (d_ws != nullptr);

    if (pre) {
        __bf16* xp = (__bf16*)d_ws;
        xpack_kernel<<<dim3((M_ROWS * IN_F / 8) / 256), dim3(256), 0, stream>>>(x, xp);
        bias_init_kernel<<<dim3((M_ROWS * OUT_F / 4) / 256), dim3(256), 0, stream>>>(bias, out);
        qgemm7_kernel<<<dim3(256), dim3(THREADS), 0, stream>>>(xp, Wq, scales, out);
    } else {
        qgemm_fallback<<<dim3(512), dim3(256), 0, stream>>>(x, Wq, scales, bias, out);
    }
}

// Round 9
// 142.264 us; speedup vs baseline: 1.1792x; 1.1792x over previous
//
#include <hip/hip_runtime.h>

#define IN_F 4096
#define OUT_F 16384
#define M_ROWS 512

#define BM 128
#define BN 128
#define BK 64
#define NKT (IN_F / BK)    // 64
#define THREADS 256

typedef __bf16 bf16x8_t __attribute__((ext_vector_type(8)));
typedef float f32x4_t __attribute__((ext_vector_type(4)));
typedef int i32x4_t __attribute__((ext_vector_type(4)));

__device__ __forceinline__ void gld16(const void* g, void* l) {
    __builtin_amdgcn_global_load_lds(
        (const __attribute__((address_space(1))) void*)g,
        (__attribute__((address_space(3))) void*)l,
        16 /*bytes, literal*/, 0, 0);
}

// ---------------- pre-pass: x fp32 -> bf16, swizzled LDS tile image ----------------
// xp = [4 mt][64 kt] tiles of 128r x 64c bf16 (16 KB each), stored as the exact
// linear byte image gld16 drops into LDS. GEMM reads elem (r, k) at LDS byte
// r*128 + ((k>>3) ^ (r&7))*16 + (k&7)*2, so linear slot (r, ch) holds
// x[mt*128+r][kt*64 + ((ch ^ (r&7))<<3) + j].  (chunk = 16B = 8 bf16)
__global__ __launch_bounds__(256)
void xpack_kernel(const float* __restrict__ x, __bf16* __restrict__ xp) {
    const int tid = blockIdx.x * 256 + (int)threadIdx.x;   // 262144 threads, 1 chunk each
    const int tile = tid >> 10;            // 1024 chunks per tile; tile = mt*64+kt
    const int r = (tid >> 3) & 127;
    const int ch = tid & 7;
    const int mt = tile >> 6;
    const int kt = tile & 63;
    const int gcol = kt * 64 + ((ch ^ (r & 7)) << 3);
    const float* src = x + (size_t)(mt * 128 + r) * IN_F + gcol;
    f32x4_t a = *(const f32x4_t*)(src);
    f32x4_t b = *(const f32x4_t*)(src + 4);
    bf16x8_t o;
    o[0] = (__bf16)a[0]; o[1] = (__bf16)a[1]; o[2] = (__bf16)a[2]; o[3] = (__bf16)a[3];
    o[4] = (__bf16)b[0]; o[5] = (__bf16)b[1]; o[6] = (__bf16)b[2]; o[7] = (__bf16)b[3];
    *(bf16x8_t*)(xp + (size_t)tid * 8) = o;
}

// ---------------- main GEMM: m97 structure, 2 blocks/CU ----------------
// grid 512 = 4 mt x 128 nt, 4 waves (2x2, 64x64 each). LDS 48 KB (A 16 + B 32).
// XCD k (bid&7) owns nt in [16k,16k+16), mt-fastest -> concurrent mt-quad shares
// each Wq panel inside one L2 (stream dedup). Single-buffer, 2 barriers/kt (m97).
__global__ __launch_bounds__(THREADS, 2)
void qgemm9_kernel(const __bf16* __restrict__ xp, const int* __restrict__ Wq,
                   const float* __restrict__ scales, const float* __restrict__ bias,
                   float* __restrict__ out) {
    __shared__ __align__(16) unsigned char sA[BM * BK * 2];   // 16 KB bf16, swizzled image
    __shared__ __align__(16) unsigned char sB[BN * BK * 4];   // 32 KB int32, swizzled image

    const int bid = (int)blockIdx.x;
    const int s = bid >> 3;                      // 0..63 within XCD
    const int nt = (bid & 7) * 16 + (s >> 2);    // 0..127
    const int mt = s & 3;                        // fastest: mt-quad concurrent on one XCD
    const int brow = mt * BM;
    const int bcol = nt * BN;

    const int t = (int)threadIdx.x;
    const int lane = t & 63;
    const int wid = t >> 6;        // 4 waves
    const int wr = wid >> 1;       // 0..1
    const int wc = wid & 1;        // 0..1

    // ---- A DMA: 16 KB/kt = 4 gld16 sweeps (256 thr x 16 B = 4 KB per sweep) ----
    const __bf16* xt = xp + (size_t)(mt * NKT) * (BM * BK) + t * 8;  // + kt*8192 elems
    const int ldsA0 = wid * 1024;  // wave-uniform; HW adds lane*16; + i*4096 per sweep

    // ---- B DMA: 32 KB/kt = 8 gld16 sweeps, global-side chunk swizzle ----
    // Sweep i dest byte p = i*4096 + t*16 -> row r = i*16 + (t>>4), chunk c' = t&15.
    // (r&7) = ((t>>4)&7), invariant across i -> one XOR base serves all sweeps.
    const int rB0 = t >> 4;                          // 0..15
    const int ccB = (((t & 15) ^ (rB0 & 7)) << 2);   // int32 offset of fetched 16B chunk
    const int* wg = Wq + (size_t)(bcol + rB0) * IN_F + ccB;
    const int ldsB0 = wid * 1024;  // + i*4096 per sweep

    f32x4_t acc[4][4];
#pragma unroll
    for (int i = 0; i < 4; ++i)
#pragma unroll
        for (int j = 0; j < 4; ++j) {
            f32x4_t z = {0.f, 0.f, 0.f, 0.f};
            acc[i][j] = z;
        }

    // ---- fragment bases (swizzle s = lane&7; row+16 invariant) ----
    const int la = lane & 15;
    const int g = lane >> 4;       // k-quartet 0..3
    const int sw = lane & 7;
    const int arow0 = wr * 64 + la;         // + m*16
    const int brow0 = wc * 64 + la;         // + n*16

#pragma unroll 1
    for (int kt = 0; kt < NKT; ++kt) {
        __syncthreads();   // readers of the (single) buffer done

        // ---- stage tile kt: A 4 sweeps + B 8 sweeps ----
        {
            const __bf16* sa_ = xt + (size_t)kt * (BM * BK);
#pragma unroll
            for (int i = 0; i < 4; ++i)
                gld16(sa_ + i * 2048, &sA[0] + ldsA0 + i * 4096);
            const int* wp = wg + (size_t)kt * BK;
#pragma unroll
            for (int i = 0; i < 8; ++i)
                gld16(wp + (size_t)i * 16 * IN_F, &sB[0] + ldsB0 + i * 4096);
        }

        __syncthreads();   // vmcnt(0) drain + barrier: tile resident (m97 schedule)

#pragma unroll
        for (int ks = 0; ks < 2; ++ks) {
            // A frags: chunk ch = ks*4+g at row r_, slot = ch ^ (r_&7) = ch ^ sw
            bf16x8_t af[4];
#pragma unroll
            for (int m = 0; m < 4; ++m) {
                const int r_ = arow0 + m * 16;
                af[m] = *(const bf16x8_t*)(&sA[0] + r_ * 128 + (((ks * 4 + g) ^ sw) << 4));
            }
            // B frags: int32 chunks cc, cc+1 at row rn (slot = chunk ^ sw); cvt -> bf16
            bf16x8_t bf[4];
#pragma unroll
            for (int n = 0; n < 4; ++n) {
                const int rn = brow0 + n * 16;
                const int cc = ks * 8 + g * 2;
                const unsigned char* pb = &sB[0] + rn * 256;
                i32x4_t lo = *(const i32x4_t*)(pb + (((cc + 0) ^ sw) << 4));
                i32x4_t hi = *(const i32x4_t*)(pb + (((cc + 1) ^ sw) << 4));
#pragma unroll
                for (int j = 0; j < 4; ++j) {
                    bf[n][j] = (__bf16)(float)lo[j];
                    bf[n][4 + j] = (__bf16)(float)hi[j];
                }
            }
#pragma unroll
            for (int m = 0; m < 4; ++m)
#pragma unroll
                for (int n = 0; n < 4; ++n)
                    acc[m][n] = __builtin_amdgcn_mfma_f32_16x16x32_bf16(
                        af[m], bf[n], acc[m][n], 0, 0, 0);
        }
    }

    // ---- epilogue: per-col dequant scale + bias, direct fp32 store ----
    // C/D layout: col = lane&15, row = (lane>>4)*4 + reg (m89-verified, r1-r7-validated)
    const int orow0 = brow + wr * 64 + (g << 2);
    const int ocol0 = bcol + wc * 64 + la;
#pragma unroll
    for (int n = 0; n < 4; ++n) {
        const int c = ocol0 + n * 16;
        const float sc = scales[c];
        const float bs = bias[c];
#pragma unroll
        for (int m = 0; m < 4; ++m) {
            const int r = orow0 + m * 16;
            float* po = out + (size_t)r * OUT_F + c;
#pragma unroll
            for (int j = 0; j < 4; ++j) {
                po[(size_t)j * OUT_F] = acc[m][n][j] * sc + bs;
            }
        }
    }
}

// ---------------- fallback (no workspace): round-1 kernel, known-correct ----------------
__global__ __launch_bounds__(256, 2)
void qgemm_fallback(const float* __restrict__ x, const int* __restrict__ Wq,
                    const float* __restrict__ scales, const float* __restrict__ bias,
                    float* __restrict__ out) {
    __shared__ __align__(16) unsigned char fA[128 * 64 * 2];
    __shared__ __align__(16) unsigned char fB[128 * 64 * 2];

    const int bid = (int)blockIdx.x;
    const int gsw = (bid & 7) * 64 + (bid >> 3);
    const int mt = gsw & 3;
    const int ntf = gsw >> 2;
    const int brow = mt * 128;
    const int bcolf = ntf * 128;

    const int t = (int)threadIdx.x;
    const int lane = t & 63;
    const int wid = t >> 6;
    const int wr = wid >> 1;
    const int wc = wid & 1;

    const int srow = t >> 4;
    const int sc4 = t & 15;

    const float* xg = x + (size_t)(brow + srow) * IN_F + sc4 * 4;
    const int* wgf = Wq + (size_t)(bcolf + srow) * IN_F + sc4 * 4;

    f32x4_t acc[4][4];
#pragma unroll
    for (int i = 0; i < 4; ++i)
#pragma unroll
        for (int j = 0; j < 4; ++j) {
            f32x4_t z = {0.f, 0.f, 0.f, 0.f};
            acc[i][j] = z;
        }

    const int frow_a = wr * 64 + (lane & 15);
    const int frow_b = wc * 64 + (lane & 15);
    const int fk = (lane >> 4) * 16;

#pragma unroll 1
    for (int kt = 0; kt < IN_F / 64; ++kt) {
        const int k0 = kt * 64;
        f32x4_t av[8];
        i32x4_t bvf[8];
#pragma unroll
        for (int i = 0; i < 8; ++i) {
            av[i] = *(const f32x4_t*)(xg + k0 + (size_t)i * 16 * IN_F);
            bvf[i] = *(const i32x4_t*)(wgf + k0 + (size_t)i * 16 * IN_F);
        }
        __syncthreads();
#pragma unroll
        for (int i = 0; i < 8; ++i) {
            const int row = srow + i * 16;
            unsigned off = (unsigned)(row * 128 + sc4 * 8);
            off ^= (unsigned)(row & 7) << 4;
            __bf16 pa[4], pb[4];
#pragma unroll
            for (int j = 0; j < 4; ++j) {
                pa[j] = (__bf16)av[i][j];
                pb[j] = (__bf16)(float)bvf[i][j];
            }
            *(unsigned long long*)(fA + off) = *(unsigned long long*)pa;
            *(unsigned long long*)(fB + off) = *(unsigned long long*)pb;
        }
        __syncthreads();
#pragma unroll
        for (int ks = 0; ks < 2; ++ks) {
            bf16x8_t afv[4], bfv[4];
#pragma unroll
            for (int m = 0; m < 4; ++m) {
                const int row = frow_a + m * 16;
                afv[m] = *(const bf16x8_t*)(fA + (row * 128 + ((ks * 64 + fk) ^ ((row & 7) << 4))));
            }
#pragma unroll
            for (int n = 0; n < 4; ++n) {
                const int row = frow_b + n * 16;
                bfv[n] = *(const bf16x8_t*)(fB + (row * 128 + ((ks * 64 + fk) ^ ((row & 7) << 4))));
            }
#pragma unroll
            for (int m = 0; m < 4; ++m)
#pragma unroll
                for (int n = 0; n < 4; ++n)
                    acc[m][n] = __builtin_amdgcn_mfma_f32_16x16x32_bf16(
                        afv[m], bfv[n], acc[m][n], 0, 0, 0);
        }
    }

    const int orow = brow + wr * 64 + ((lane >> 4) << 2);
    const int ocol = bcolf + wc * 64 + (lane & 15);
#pragma unroll
    for (int n = 0; n < 4; ++n) {
        const int c = ocol + n * 16;
        const float sc = scales[c];
        const float bs = bias[c];
#pragma unroll
        for (int m = 0; m < 4; ++m) {
            const int r = orow + m * 16;
            float* po = out + (size_t)r * OUT_F + c;
#pragma unroll
            for (int j = 0; j < 4; ++j) {
                po[(size_t)j * OUT_F] = acc[m][n][j] * sc + bs;
            }
        }
    }
}

extern "C" void kernel_launch(void* const* d_in, const int* in_sizes, int n_in,
                              void* d_out, int out_size, void* d_ws, size_t ws_size,
                              hipStream_t stream) {
    const float* x = (const float*)d_in[0];
    const int* Wq = (const int*)d_in[1];
    const float* scales = (const float*)d_in[2];
    const float* bias = (const float*)d_in[3];
    float* out = (float*)d_out;

    const size_t xp_bytes = (size_t)M_ROWS * IN_F * 2;  // 4 MB
    const bool pre = (ws_size >= xp_bytes) && (d_ws != nullptr);

    if (pre) {
        __bf16* xp = (__bf16*)d_ws;
        xpack_kernel<<<dim3((M_ROWS * IN_F / 8) / 256), dim3(256), 0, stream>>>(x, xp);
        qgemm9_kernel<<<dim3(512), dim3(THREADS), 0, stream>>>(xp, Wq, scales, bias, out);
    } else {
        qgemm_fallback<<<dim3(512), dim3(256), 0, stream>>>(x, Wq, scales, bias, out);
    }
}